// Round 12
// baseline (3674.994 us; speedup 1.0000x reference)
//
#include <hip/hip_runtime.h>
#include <cstdint>
#include <cstddef>

namespace {

constexpr int H    = 300;
constexpr int G4   = 1200;   // 4*H
constexpr int B    = 128;
constexpr int T    = 512;
constexpr int NVOC = 2514;

typedef __attribute__((ext_vector_type(8))) short  short8;
typedef __attribute__((ext_vector_type(4))) float  f32x4;

__device__ __forceinline__ float sigm(float x)     { return 1.f / (1.f + __expf(-x)); }
__device__ __forceinline__ float tanhfast(float x) { return 1.f - 2.f / (__expf(2.f*x) + 1.f); }

__device__ __forceinline__ unsigned short bf16_rn(float f) {
    unsigned u = __float_as_uint(f);
    u += 0x7FFFu + ((u >> 16) & 1u);
    return (unsigned short)(u >> 16);
}
__device__ __forceinline__ float bf16_f(unsigned short s) {
    return __uint_as_float(((unsigned)s) << 16);
}
__device__ __forceinline__ unsigned pack2(unsigned short lo16, unsigned short hi16) {
    return (unsigned)lo16 | ((unsigned)hi16 << 16);
}

// packed h layout: idx(t, hg, b, u) = ((t*15 + hg)*128 + b)*20 + u
constexpr int TSEG = 15 * 128 * 20;   // floats per t-slice (38400)

// ---------------------------------------------------------------------------
// MFMA split-precision GEMM (unchanged from round 10/11 — deliberately not
// touched this round; single-variable A/B on the recurrence).
// ---------------------------------------------------------------------------
template<int AMODE, bool HASB2>
__global__ __launch_bounds__(256)
void gemm_mfma(const float* __restrict__ A, const float* __restrict__ W,
               const float* __restrict__ b1, const float* __restrict__ b2,
               const int* __restrict__ tok, float* __restrict__ out, int N)
{
    __shared__ __align__(16) unsigned short Ah[128][40], Al[128][40];
    __shared__ __align__(16) unsigned short Wh[128][40], Wl[128][40];

    const int tid = threadIdx.x;
    const int m0 = blockIdx.y * 128, n0 = blockIdx.x * 128;
    const int rl = tid >> 1, cb = (tid & 1) * 16;

    const int m = m0 + rl;
    const float* aptr;
    if (AMODE == 0) aptr = A + (size_t)m * H;
    else if (AMODE == 3) aptr = A + (size_t)(m & 511) * TSEG + (m >> 9) * 20;
    else {
        const int q = ((m & 127) << 9) + (m >> 7);
        aptr = A + (size_t)((AMODE == 1) ? tok[q] : q) * H;
    }
    const int nrow = n0 + rl;
    const float* wptr = W + (size_t)nrow * H;
    const bool nok = (nrow < N);

    const int wv = tid >> 6, lane = tid & 63;
    const int mw = (wv >> 1) * 64, nw = (wv & 1) * 64;
    const int kg = lane >> 4, mm = lane & 15;

    f32x4 acc[4][4];
#pragma unroll
    for (int i = 0; i < 4; ++i)
#pragma unroll
        for (int j = 0; j < 4; ++j) acc[i][j] = (f32x4){0.f, 0.f, 0.f, 0.f};

    for (int kt = 0; kt < 10; ++kt) {
        const int kbase = kt * 32;
        float4 av[4], wvv[4];
#pragma unroll
        for (int j = 0; j < 4; ++j) {
            const int col = kbase + cb + j * 4;
            const bool kv = (col <= H - 4);
            if (AMODE == 3)
                av[j] = kv ? *(const float4*)(aptr + (col / 20) * 2560 + col % 20)
                           : make_float4(0, 0, 0, 0);
            else
                av[j] = kv ? *(const float4*)(aptr + col) : make_float4(0, 0, 0, 0);
            wvv[j] = (kv && nok) ? *(const float4*)(wptr + col) : make_float4(0, 0, 0, 0);
        }
        __syncthreads();
#pragma unroll
        for (int j = 0; j < 4; ++j) {
            const float a[4] = {av[j].x,  av[j].y,  av[j].z,  av[j].w};
            const float w[4] = {wvv[j].x, wvv[j].y, wvv[j].z, wvv[j].w};
            unsigned short ah[4], al_[4], wh[4], wl[4];
#pragma unroll
            for (int e = 0; e < 4; ++e) {
                ah[e] = bf16_rn(a[e]); al_[e] = bf16_rn(a[e] - bf16_f(ah[e]));
                wh[e] = bf16_rn(w[e]); wl[e]  = bf16_rn(w[e] - bf16_f(wh[e]));
            }
            const int cc = cb + j * 4;
            *(uint2*)&Ah[rl][cc] = make_uint2(pack2(ah[0],ah[1]),  pack2(ah[2],ah[3]));
            *(uint2*)&Al[rl][cc] = make_uint2(pack2(al_[0],al_[1]),pack2(al_[2],al_[3]));
            *(uint2*)&Wh[rl][cc] = make_uint2(pack2(wh[0],wh[1]),  pack2(wh[2],wh[3]));
            *(uint2*)&Wl[rl][cc] = make_uint2(pack2(wl[0],wl[1]),  pack2(wl[2],wl[3]));
        }
        __syncthreads();

        short8 fah[4], fal[4], fbh[4], fbl[4];
#pragma unroll
        for (int f = 0; f < 4; ++f) {
            fah[f] = *(const short8*)&Ah[mw + f*16 + mm][kg*8];
            fal[f] = *(const short8*)&Al[mw + f*16 + mm][kg*8];
            fbh[f] = *(const short8*)&Wh[nw + f*16 + mm][kg*8];
            fbl[f] = *(const short8*)&Wl[nw + f*16 + mm][kg*8];
        }
#pragma unroll
        for (int mf = 0; mf < 4; ++mf)
#pragma unroll
            for (int nf = 0; nf < 4; ++nf) {
                acc[mf][nf] = __builtin_amdgcn_mfma_f32_16x16x32_bf16(fah[mf], fbh[nf], acc[mf][nf], 0, 0, 0);
                acc[mf][nf] = __builtin_amdgcn_mfma_f32_16x16x32_bf16(fal[mf], fbh[nf], acc[mf][nf], 0, 0, 0);
                acc[mf][nf] = __builtin_amdgcn_mfma_f32_16x16x32_bf16(fah[mf], fbl[nf], acc[mf][nf], 0, 0, 0);
            }
    }

    float bias[4];
#pragma unroll
    for (int nf = 0; nf < 4; ++nf) {
        const int n = n0 + nw + nf*16 + mm;
        float v = 0.f;
        if (n < N) { v = b1[n]; if (HASB2) v += b2[n]; }
        bias[nf] = v;
    }
    const int qr = lane >> 4;
#pragma unroll
    for (int mf = 0; mf < 4; ++mf) {
        const int row = m0 + mw + mf*16 + qr*4;
        float* orow = out + (size_t)row * N;
#pragma unroll
        for (int nf = 0; nf < 4; ++nf) {
            const int n = n0 + nw + nf*16 + mm;
            if (n < N) {
#pragma unroll
                for (int r = 0; r < 4; ++r)
                    orow[(size_t)r * N + n] = acc[mf][nf][r] + bias[nf];
            }
        }
    }
}

// ---------------------------------------------------------------------------
// Sentinel fill (data-as-flag protocol; h in (-1,1) is never NaN)
// ---------------------------------------------------------------------------
constexpr unsigned SENT = 0x7FB00F0Fu;

__global__ __launch_bounds__(256)
void sentinel_fill(uint4* __restrict__ p, size_t n4)
{
    const uint4 s = make_uint4(SENT, SENT, SENT, SENT);
    size_t i = (size_t)blockIdx.x * blockDim.x + threadIdx.x;
    const size_t stride = (size_t)gridDim.x * blockDim.x;
    for (; i < n4; i += stride) p[i] = s;
}

// ---------------------------------------------------------------------------
// v12 = v11 with ONE change: __launch_bounds__(512, 2) on lstm_fused.
// Round-11 counters showed VGPR_Count=128, but every wave's resident
// B-fragments alone need 160 VGPRs (40 x short8) — the compiler was capping
// at 4-waves/SIMD occupancy and silently spilling the "W resident in VGPRs"
// arrays to scratch, re-loading ~0.5 MB/block/iteration from L2 (~60 TB over
// the dispatch ~ 1.7 ms at the L2 ceiling). The block runs exactly 8 waves on
// 4 SIMDs = 2 waves/SIMD, so min-2-waves/EU is the true occupancy: VGPR cap
// becomes 256 and the ~220-register working set fits with no spill.
// ---------------------------------------------------------------------------
constexpr int HGC = 15;
constexpr int BGC = 16;
constexpr int NWG = HGC * BGC;   // 240
constexpr int A2OFF = 20480;
constexpr int APARF = 40960;
constexpr int GDOFF = 2 * APARF;
constexpr int FLDS  = GDOFF + 10 * 8 * 16 * 4;   // 87040 B

struct StageCtx {
    size_t   src64[5];   // b64 index within a t-slice
    int      aoffHi[5];  // A-fragment hi-plane byte offset
    unsigned pend0;
};

__device__ __forceinline__ void stage_init(StageCtx& S, int lane, int bg,
                                           int base_hg, int nchunks, int region)
{
    const int words = nchunks * 80;   // 80 b64 words per (hg,bg) chunk
    S.pend0 = 0;
#pragma unroll
    for (int j = 0; j < 5; ++j) {
        const int s = lane + 64 * j;
        const bool ok = (s < words);
        const int chunk = ok ? s / 80 : 0, rem = ok ? s % 80 : 0;
        const int hg = base_hg + chunk;
        S.src64[j] = (size_t)(hg * 128 + bg * 8) * 10 + rem;
        const int u2 = rem * 2, b_loc = u2 / 20, u = u2 % 20;
        const int k = hg * 20 + u;
        const int kt = k >> 5, kq = (k >> 3) & 3, pos = k & 7;
        S.aoffHi[j] = region + ((kt * 2) * 4 + kq) * 256 + b_loc * 16 + pos * 2;
        if (ok) S.pend0 |= 1u << j;
    }
}

__device__ __forceinline__ void stage_poll(const StageCtx& S,
                                           const float* __restrict__ slice,
                                           unsigned char* Ap)
{
    const unsigned long long* s64 = (const unsigned long long*)slice;
    unsigned long long val[5];
    unsigned pend = S.pend0;
    while (__any(pend != 0)) {
        unsigned long long w[5];
#pragma unroll
        for (int j = 0; j < 5; ++j)
            if (pend & (1u << j))
                w[j] = __hip_atomic_load(s64 + S.src64[j], __ATOMIC_RELAXED,
                                         __HIP_MEMORY_SCOPE_AGENT);
#pragma unroll
        for (int j = 0; j < 5; ++j)
            if (pend & (1u << j)) {
                const unsigned long long x = w[j];
                if ((unsigned)x != SENT && (unsigned)(x >> 32) != SENT) {
                    val[j] = x; pend &= ~(1u << j);
                }
            }
    }
#pragma unroll
    for (int j = 0; j < 5; ++j)
        if (S.pend0 & (1u << j)) {
            const float v0 = __uint_as_float((unsigned)val[j]);
            const float v1 = __uint_as_float((unsigned)(val[j] >> 32));
            const unsigned short h0 = bf16_rn(v0), h1_ = bf16_rn(v1);
            *(unsigned*)(Ap + S.aoffHi[j]) = pack2(h0, h1_);
            *(unsigned*)(Ap + S.aoffHi[j] + 1024) =
                pack2(bf16_rn(v0 - bf16_f(h0)), bf16_rn(v1 - bf16_f(h1_)));
        }
}

// ---- L0 waves (wv 0-2): stage h1 chunks, MFMA, L0 update + h1 publish ------
template<int NTN>
__device__ void fused_g0(int lane, int hg, int bg, int NT0, int base_hg,
                         int nchunks,
                         const float* __restrict__ xg0,
                         const float* __restrict__ Whh0,
                         float* __restrict__ h1p,
                         unsigned char* __restrict__ Abuf, float (*gd)[8][16])
{
    const int kg = lane >> 4, mm = lane & 15;

    short8 bh[10][NTN], bl[10][NTN];
#pragma unroll
    for (int kt = 0; kt < 10; ++kt)
#pragma unroll
        for (int j = 0; j < NTN; ++j) {
            const int c = (NT0 + j) * 16 + mm;
            const int grow = (c & 3) * H + hg * 20 + (c >> 2);
            short8 hi, lo;
#pragma unroll
            for (int e = 0; e < 8; ++e) {
                const int k = kt * 32 + kg * 8 + e;
                const float v = (k < H) ? Whh0[(size_t)grow * H + k] : 0.f;
                const unsigned short h16 = bf16_rn(v);
                hi[e] = (short)h16;
                lo[e] = (short)bf16_rn(v - bf16_f(h16));
            }
            bh[kt][j] = hi; bl[kt][j] = lo;
        }

    StageCtx S; stage_init(S, lane, bg, base_hg, nchunks, 0);

    const int sh = (NTN == 2) ? 3 : 2;
    const bool upd = lane < (NTN << 5);
    const int b_u = lane >> sh, u4 = lane & ((1 << sh) - 1);
    const int u_loc = NT0 * 4 + u4;
    const int ntl = NT0 + (u4 >> 2), u_rel = u4 & 3;
    float cst = 0.f;

    const float* xb0 = xg0 + (size_t)(bg * 8 + b_u) * G4 + hg * 20 + u_loc;
    float* hst = h1p + ((size_t)hg * 128 + bg * 8 + b_u) * 20 + u_loc;

    for (int it = 0; it <= T; ++it) {
        float xv0 = 0.f, xv1 = 0.f, xv2 = 0.f, xv3 = 0.f;
        if (upd && it < T) {
            const float* xb = xb0 + (size_t)it * B * G4;
            xv0 = xb[0]; xv1 = xb[H]; xv2 = xb[2 * H]; xv3 = xb[3 * H];
        }
        unsigned char* Ap = Abuf + (it & 1) * APARF;
        if (it >= 1) stage_poll(S, h1p + (size_t)(it - 1) * TSEG, Ap);
        __syncthreads();

        if (it < T) {
            f32x4 a0 = (f32x4){0.f,0.f,0.f,0.f}, a1 = (f32x4){0.f,0.f,0.f,0.f};
#pragma unroll
            for (int kt = 0; kt < 10; ++kt) {
                const short8 ah = *(const short8*)(Ap + ((kt*2+0)*4 + kg)*256 + mm*16);
                const short8 al = *(const short8*)(Ap + ((kt*2+1)*4 + kg)*256 + mm*16);
                a0 = __builtin_amdgcn_mfma_f32_16x16x32_bf16(ah, bh[kt][0], a0, 0, 0, 0);
                a0 = __builtin_amdgcn_mfma_f32_16x16x32_bf16(al, bh[kt][0], a0, 0, 0, 0);
                a0 = __builtin_amdgcn_mfma_f32_16x16x32_bf16(ah, bl[kt][0], a0, 0, 0, 0);
                if (NTN > 1) {
                    a1 = __builtin_amdgcn_mfma_f32_16x16x32_bf16(ah, bh[kt][1], a1, 0, 0, 0);
                    a1 = __builtin_amdgcn_mfma_f32_16x16x32_bf16(al, bh[kt][1], a1, 0, 0, 0);
                    a1 = __builtin_amdgcn_mfma_f32_16x16x32_bf16(ah, bl[kt][1], a1, 0, 0, 0);
                }
            }
            if (lane < 32) {
                const int br = (lane >> 4) * 4;
#pragma unroll
                for (int r = 0; r < 4; ++r) gd[NT0][br + r][mm] = a0[r];
                if (NTN > 1)
#pragma unroll
                    for (int r = 0; r < 4; ++r) gd[NT0 + 1][br + r][mm] = a1[r];
            }
            if (upd) {
                const float* g4 = &gd[ntl][b_u][u_rel * 4];
                const float gi = xv0 + g4[0], gf = xv1 + g4[1];
                const float gz = xv2 + g4[2], go = xv3 + g4[3];
                const float iG = sigm(gi), fG = sigm(gf);
                const float zG = tanhfast(gz), oG = sigm(go);
                cst = fmaf(fG, cst, iG * zG);
                const float hv = oG * tanhfast(cst);
                __hip_atomic_store(hst + (size_t)it * TSEG, hv,
                                   __ATOMIC_RELAXED, __HIP_MEMORY_SCOPE_AGENT);
            }
        }
    }
}

// ---- L1 waves (wv 3-7): stage (h1|h2) chunks, dual MFMA, L1 update ---------
__device__ void fused_g1(int lane, int hg, int bg, int ntg,
                         const float* __restrict__ stage_src, int stage_delta,
                         int stage_region, int base_hg, int nchunks,
                         const float* __restrict__ Wih1,
                         const float* __restrict__ Whh1,
                         const float* __restrict__ bih1,
                         const float* __restrict__ bhh1,
                         float* __restrict__ h2p,
                         unsigned char* __restrict__ Abuf, float (*gd)[8][16])
{
    const int kg = lane >> 4, mm = lane & 15;
    const int c = ntg * 16 + mm;
    const int grow = (c & 3) * H + hg * 20 + (c >> 2);

    short8 bIh[10], bIl[10], bHh[10], bHl[10];
#pragma unroll
    for (int kt = 0; kt < 10; ++kt) {
        short8 ih, il, hh, hl;
#pragma unroll
        for (int e = 0; e < 8; ++e) {
            const int k = kt * 32 + kg * 8 + e;
            const float vi = (k < H) ? Wih1[(size_t)grow * H + k] : 0.f;
            const float vh = (k < H) ? Whh1[(size_t)grow * H + k] : 0.f;
            const unsigned short i16 = bf16_rn(vi), h16 = bf16_rn(vh);
            ih[e] = (short)i16; il[e] = (short)bf16_rn(vi - bf16_f(i16));
            hh[e] = (short)h16; hl[e] = (short)bf16_rn(vh - bf16_f(h16));
        }
        bIh[kt] = ih; bIl[kt] = il; bHh[kt] = hh; bHl[kt] = hl;
    }

    StageCtx S; stage_init(S, lane, bg, base_hg, nchunks, stage_region);

    const bool upd = lane < 32;
    const int b_u = lane >> 2, u4 = lane & 3;
    const int u_loc = ntg * 4 + u4;
    float bias[4];
#pragma unroll
    for (int g = 0; g < 4; ++g) {
        const int gr = g * H + hg * 20 + u_loc;
        bias[g] = bih1[gr] + bhh1[gr];
    }
    float cst = 0.f;
    float* hst = h2p + ((size_t)hg * 128 + bg * 8 + b_u) * 20 + u_loc;

    for (int it = 0; it <= T; ++it) {
        unsigned char* Ap = Abuf + (it & 1) * APARF;
        if (it >= stage_delta)
            stage_poll(S, stage_src + (size_t)(it - stage_delta) * TSEG, Ap);
        __syncthreads();

        if (it >= 1) {
            f32x4 acc = (f32x4){0.f, 0.f, 0.f, 0.f};
#pragma unroll
            for (int kt = 0; kt < 10; ++kt) {   // h1[it-1] @ Wih1^T
                const short8 ah = *(const short8*)(Ap + ((kt*2+0)*4 + kg)*256 + mm*16);
                const short8 al = *(const short8*)(Ap + ((kt*2+1)*4 + kg)*256 + mm*16);
                acc = __builtin_amdgcn_mfma_f32_16x16x32_bf16(ah, bIh[kt], acc, 0, 0, 0);
                acc = __builtin_amdgcn_mfma_f32_16x16x32_bf16(al, bIh[kt], acc, 0, 0, 0);
                acc = __builtin_amdgcn_mfma_f32_16x16x32_bf16(ah, bIl[kt], acc, 0, 0, 0);
            }
#pragma unroll
            for (int kt = 0; kt < 10; ++kt) {   // h2[it-2] @ Whh1^T
                const short8 ah = *(const short8*)(Ap + A2OFF + ((kt*2+0)*4 + kg)*256 + mm*16);
                const short8 al = *(const short8*)(Ap + A2OFF + ((kt*2+1)*4 + kg)*256 + mm*16);
                acc = __builtin_amdgcn_mfma_f32_16x16x32_bf16(ah, bHh[kt], acc, 0, 0, 0);
                acc = __builtin_amdgcn_mfma_f32_16x16x32_bf16(al, bHh[kt], acc, 0, 0, 0);
                acc = __builtin_amdgcn_mfma_f32_16x16x32_bf16(ah, bHl[kt], acc, 0, 0, 0);
            }
            if (lane < 32) {
                const int br = (lane >> 4) * 4;
#pragma unroll
                for (int r = 0; r < 4; ++r) gd[5 + ntg][br + r][mm] = acc[r];
            }
            if (upd) {
                const float* g4 = &gd[5 + ntg][b_u][u4 * 4];
                const float gi = bias[0] + g4[0], gf = bias[1] + g4[1];
                const float gz = bias[2] + g4[2], go = bias[3] + g4[3];
                const float iG = sigm(gi), fG = sigm(gf);
                const float zG = tanhfast(gz), oG = sigm(go);
                cst = fmaf(fG, cst, iG * zG);
                const float hv = oG * tanhfast(cst);
                __hip_atomic_store(hst + (size_t)(it - 1) * TSEG, hv,
                                   __ATOMIC_RELAXED, __HIP_MEMORY_SCOPE_AGENT);
            }
        }
    }
}

__global__ __launch_bounds__(512, 2)   // <-- THE round-12 change: 2 waves/EU
void lstm_fused(const float* __restrict__ xg0,                 //     -> 256-VGPR cap, B-frags stay resident
                const float* __restrict__ Whh0,
                const float* __restrict__ Wih1,
                const float* __restrict__ Whh1,
                const float* __restrict__ bih1,
                const float* __restrict__ bhh1,
                float* __restrict__ h1p, float* __restrict__ h2p)
{
    extern __shared__ unsigned char smem[];
    unsigned char* Abuf = smem;
    float (*gd)[8][16] = (float(*)[8][16])(smem + GDOFF);

    const int tid = threadIdx.x, wv = tid >> 6, lane = tid & 63;
    const int hg = blockIdx.x % HGC, bg = blockIdx.x / HGC;

    for (int i = tid; i < FLDS / 16; i += 512)
        ((uint4*)smem)[i] = make_uint4(0, 0, 0, 0);
    __syncthreads();

    if      (wv == 0) fused_g0<2>(lane, hg, bg, 0,  0, 4, xg0, Whh0, h1p, Abuf, gd);
    else if (wv == 1) fused_g0<2>(lane, hg, bg, 2,  4, 4, xg0, Whh0, h1p, Abuf, gd);
    else if (wv == 2) fused_g0<1>(lane, hg, bg, 4,  8, 4, xg0, Whh0, h1p, Abuf, gd);
    else if (wv == 3) fused_g1(lane, hg, bg, 0, h1p, 1, 0,     12, 3,
                               Wih1, Whh1, bih1, bhh1, h2p, Abuf, gd);
    else              fused_g1(lane, hg, bg, wv - 3, h2p, 2, A2OFF,
                               (wv - 4) * 4, (wv == 7) ? 3 : 4,
                               Wih1, Whh1, bih1, bhh1, h2p, Abuf, gd);
}

} // anonymous namespace

// ---------------------------------------------------------------------------
extern "C" void kernel_launch(void* const* d_in, const int* in_sizes, int n_in,
                              void* d_out, int out_size, void* d_ws, size_t ws_size,
                              hipStream_t stream)
{
    const int*   x    = (const int*)  d_in[0];
    const float* emb  = (const float*)d_in[1];
    const float* Wih0 = (const float*)d_in[2];
    const float* Whh0 = (const float*)d_in[3];
    const float* bih0 = (const float*)d_in[4];
    const float* bhh0 = (const float*)d_in[5];
    const float* Wih1 = (const float*)d_in[6];
    const float* Whh1 = (const float*)d_in[7];
    const float* bih1 = (const float*)d_in[8];
    const float* bhh1 = (const float*)d_in[9];
    const float* Wout = (const float*)d_in[10];
    const float* bout = (const float*)d_in[11];

    float* out = (float*)d_out;
    // xg0 [T][B][4H] fp32 (315 MB) aliases the output buffer (659 MB): fully
    // consumed by lstm_fused before the final GEMM overwrites d_out.
    float* xg = (float*)d_out;
    float* h1p = (float*)d_ws;                       // packed [T][15][128][20]
    float* h2p = h1p + (size_t)B * T * H;            // 78.6 MB each

    // sentinel-fill both packed h buffers (data-as-flag protocol)
    const size_t nh = 2 * (size_t)B * T * H;
    sentinel_fill<<<dim3(2048), dim3(256), 0, stream>>>((uint4*)h1p, nh / 4);

    hipFuncSetAttribute(reinterpret_cast<const void*>(lstm_fused),
                        hipFuncAttributeMaxDynamicSharedMemorySize, FLDS);

    const dim3 blk(256);
    // L0 input projection (embedding gather fused)
    gemm_mfma<1, true ><<<dim3(10, 512), blk, 0, stream>>>(emb, Wih0, bih0, bhh0, x, xg, G4);
    // fused two-layer recurrence (coalesced data-as-flag, packed-h)
    lstm_fused<<<dim3(NWG), dim3(512), FLDS, stream>>>(xg, Whh0, Wih1, Whh1,
                                                       bih1, bhh1, h1p, h2p);
    // output projection from packed h2
    gemm_mfma<3, false><<<dim3(20, 512), blk, 0, stream>>>(h2p, Wout, bout, nullptr, nullptr, out, NVOC);
}

// Round 13
// 3158.977 us; speedup vs baseline: 1.1633x; 1.1633x over previous
//
#include <hip/hip_runtime.h>
#include <cstdint>
#include <cstddef>

namespace {

constexpr int H    = 300;
constexpr int G4   = 1200;   // 4*H (unused but kept for reference)
constexpr int B    = 128;
constexpr int T    = 512;
constexpr int NVOC = 2514;
constexpr int KP   = 304;    // padded K pitch for packed bf16 hi/lo planes

typedef __attribute__((ext_vector_type(8))) short  short8;
typedef __attribute__((ext_vector_type(4))) float  f32x4;

__device__ __forceinline__ float sigm(float x)     { return 1.f / (1.f + __expf(-x)); }
__device__ __forceinline__ float tanhfast(float x) { return 1.f - 2.f / (__expf(2.f*x) + 1.f); }

__device__ __forceinline__ unsigned short bf16_rn(float f) {
    unsigned u = __float_as_uint(f);
    u += 0x7FFFu + ((u >> 16) & 1u);
    return (unsigned short)(u >> 16);
}
__device__ __forceinline__ float bf16_f(unsigned short s) {
    return __uint_as_float(((unsigned)s) << 16);
}
__device__ __forceinline__ unsigned pack2(unsigned short lo16, unsigned short hi16) {
    return (unsigned)lo16 | ((unsigned)hi16 << 16);
}
// packed value = bf16hi | (bf16lo << 16)
__device__ __forceinline__ unsigned pack_hl(float v) {
    const unsigned short hi = bf16_rn(v);
    const unsigned short lo = bf16_rn(v - bf16_f(hi));
    return (unsigned)hi | ((unsigned)lo << 16);
}

// packed h layout: idx(t, hg, b, u) = ((t*15 + hg)*128 + b)*20 + u   (u32 elems)
constexpr int TSEG = 15 * 128 * 20;   // u32 per t-slice (38400)

// sentinel: low16 = 0x7FB0 is a bf16 NaN -> impossible as the hi-plane of |h|<1
constexpr unsigned SENTP = 0x7FB07FB0u;

// ---------------------------------------------------------------------------
// Sentinel fill for packed h buffers
// ---------------------------------------------------------------------------
__global__ __launch_bounds__(256)
void sentinel_fill(uint4* __restrict__ p, size_t n4)
{
    const uint4 s = make_uint4(SENTP, SENTP, SENTP, SENTP);
    size_t i = (size_t)blockIdx.x * blockDim.x + threadIdx.x;
    const size_t stride = (size_t)gridDim.x * blockDim.x;
    for (; i < n4; i += stride) p[i] = s;
}

// ---------------------------------------------------------------------------
// Preconvert fp32 [rows][300] -> packed u32 [rows][KP] (hi|lo<<16), pad 0.
// Run once per call for emb and Wout: moves all conversion out of hot loops.
// ---------------------------------------------------------------------------
__global__ __launch_bounds__(256)
void preconv(const float* __restrict__ src, unsigned* __restrict__ dst, int rows)
{
    const size_t n = (size_t)rows * KP;
    for (size_t i = (size_t)blockIdx.x * 256 + threadIdx.x; i < n;
         i += (size_t)gridDim.x * 256) {
        const int c = (int)(i % KP), r = (int)(i / KP);
        dst[i] = (c < H) ? pack_hl(src[(size_t)r * H + c]) : 0u;
    }
}

// ---------------------------------------------------------------------------
// Logits GEMM, convert-free: A = packed h2 ([t][hg][b][20] u32), W = packed
// Wout ([NVOC][KP] u32). Staging = pure bit-shuffle. 3-pass split MFMA.
// out[m][n] = h2[b=m>>9][t=m&511] . Wout[n] + bout[n],  m = b*512+t.
// ---------------------------------------------------------------------------
__global__ __launch_bounds__(256)
void gemm_pk(const unsigned* __restrict__ Apk, const unsigned* __restrict__ Wpk,
             const float* __restrict__ b1, float* __restrict__ out, int N)
{
    __shared__ __align__(16) unsigned short Ah[128][40], Al[128][40];
    __shared__ __align__(16) unsigned short Wh[128][40], Wl[128][40];

    const int tid = threadIdx.x;
    const int m0 = blockIdx.y * 128, n0 = blockIdx.x * 128;
    const int rl = tid >> 1, cb = (tid & 1) * 16;

    const int m = m0 + rl;
    const unsigned* aptr = Apk + (size_t)(m & 511) * TSEG + (m >> 9) * 20;
    const int nrow = n0 + rl;
    const unsigned* wptr = Wpk + (size_t)nrow * KP;
    const bool nok = (nrow < N);

    const int wv = tid >> 6, lane = tid & 63;
    const int mw = (wv >> 1) * 64, nw = (wv & 1) * 64;
    const int kg = lane >> 4, mm = lane & 15;

    f32x4 acc[4][4];
#pragma unroll
    for (int i = 0; i < 4; ++i)
#pragma unroll
        for (int j = 0; j < 4; ++j) acc[i][j] = (f32x4){0.f, 0.f, 0.f, 0.f};

    for (int kt = 0; kt < 10; ++kt) {
        uint4 pa[4], pw[4];
#pragma unroll
        for (int j = 0; j < 4; ++j) {
            const int col = kt * 32 + cb + j * 4;
            pa[j] = (col < 300)
                  ? *(const uint4*)(aptr + (col / 20) * 2560 + col % 20)
                  : make_uint4(0, 0, 0, 0);
            pw[j] = (nok && col < KP) ? *(const uint4*)(wptr + col)
                                      : make_uint4(0, 0, 0, 0);
        }
        __syncthreads();
#pragma unroll
        for (int j = 0; j < 4; ++j) {
            const int cc = cb + j * 4;
            *(uint2*)&Ah[rl][cc] = make_uint2((pa[j].x & 0xFFFFu) | (pa[j].y << 16),
                                              (pa[j].z & 0xFFFFu) | (pa[j].w << 16));
            *(uint2*)&Al[rl][cc] = make_uint2((pa[j].x >> 16) | (pa[j].y & 0xFFFF0000u),
                                              (pa[j].z >> 16) | (pa[j].w & 0xFFFF0000u));
            *(uint2*)&Wh[rl][cc] = make_uint2((pw[j].x & 0xFFFFu) | (pw[j].y << 16),
                                              (pw[j].z & 0xFFFFu) | (pw[j].w << 16));
            *(uint2*)&Wl[rl][cc] = make_uint2((pw[j].x >> 16) | (pw[j].y & 0xFFFF0000u),
                                              (pw[j].z >> 16) | (pw[j].w & 0xFFFF0000u));
        }
        __syncthreads();

        short8 fah[4], fal[4], fbh[4], fbl[4];
#pragma unroll
        for (int f = 0; f < 4; ++f) {
            fah[f] = *(const short8*)&Ah[mw + f*16 + mm][kg*8];
            fal[f] = *(const short8*)&Al[mw + f*16 + mm][kg*8];
            fbh[f] = *(const short8*)&Wh[nw + f*16 + mm][kg*8];
            fbl[f] = *(const short8*)&Wl[nw + f*16 + mm][kg*8];
        }
#pragma unroll
        for (int mf = 0; mf < 4; ++mf)
#pragma unroll
            for (int nf = 0; nf < 4; ++nf) {
                acc[mf][nf] = __builtin_amdgcn_mfma_f32_16x16x32_bf16(fah[mf], fbh[nf], acc[mf][nf], 0, 0, 0);
                acc[mf][nf] = __builtin_amdgcn_mfma_f32_16x16x32_bf16(fal[mf], fbh[nf], acc[mf][nf], 0, 0, 0);
                acc[mf][nf] = __builtin_amdgcn_mfma_f32_16x16x32_bf16(fah[mf], fbl[nf], acc[mf][nf], 0, 0, 0);
            }
    }

    float bias[4];
#pragma unroll
    for (int nf = 0; nf < 4; ++nf) {
        const int n = n0 + nw + nf*16 + mm;
        bias[nf] = (n < N) ? b1[n] : 0.f;
    }
    const int qr = lane >> 4;
#pragma unroll
    for (int mf = 0; mf < 4; ++mf) {
        const int row = m0 + mw + mf*16 + qr*4;
        float* orow = out + (size_t)row * N;
#pragma unroll
        for (int nf = 0; nf < 4; ++nf) {
            const int n = n0 + nw + nf*16 + mm;
            if (n < N) {
#pragma unroll
                for (int r = 0; r < 4; ++r)
                    orow[(size_t)r * N + n] = acc[mf][nf][r] + bias[nf];
            }
        }
    }
}

// ---------------------------------------------------------------------------
// v13 fused recurrence — xg0 GEMM folded in; packed-u32 h exchange.
// 240 blocks (15 hg x 16 bg), 512 threads = 8 waves.
// Wave roles (register-balanced, B-frags hi-only except Wih0 hi+lo):
//   wv0-4: L0 n-tile wv. B: Whh0-hi (40) + Wih0 hi+lo (80). Per kt: 5 MFMAs
//          (e_hi/e_lo x Wih0_hi, e_hi x Wih0_lo, h1_hi/h1_lo x Whh0_hi).
//          Update 4 units x 8 b, publish h1[it] packed.
//   wv5,6: L1 tiles {0,1}/{2,3}; wv7: tile {4}. B: Wih1-hi + Whh1-hi per
//          tile (80). Per kt per tile: 4 MFMAs. Publish h2[it-1] packed.
// Staging: every wave e-slots (plain loads of preconverted emb rows, tokens
// from LDS — no polling, input is always valid); poll-chunks as v12
// (wv0-3: h1 quarters delta 1, wv4-7: h2 quarters delta 2) with coalesced
// packed data-as-flag (sentinel check on each u32). One barrier per iter.
// ---------------------------------------------------------------------------
constexpr int HGC = 15;
constexpr int BGC = 16;
constexpr int NWG = HGC * BGC;   // 240
constexpr int A2OFF  = 20480;    // h2 region within a parity
constexpr int EOFF   = 40960;    // e region within a parity
constexpr int APARF  = 61440;    // bytes per parity (h1 + h2 + e)
constexpr int GDOFF  = 2 * APARF;            // 122880
constexpr int TOKOFF = GDOFF + 10*8*16*4;    // 128000
constexpr int FLDS   = TOKOFF + 8*512*4;     // 144384 B

struct StageCtx {
    size_t   src64[5];
    int      aoffHi[5];
    unsigned pend0;
};

__device__ __forceinline__ void stage_init(StageCtx& S, int lane, int bg,
                                           int base_hg, int nchunks, int region)
{
    const int words = nchunks * 80;   // 80 u64-pairs per (hg,bg) chunk
    S.pend0 = 0;
#pragma unroll
    for (int j = 0; j < 5; ++j) {
        const int s = lane + 64 * j;
        const bool ok = (s < words);
        const int chunk = ok ? s / 80 : 0, rem = ok ? s % 80 : 0;
        const int hg = base_hg + chunk;
        S.src64[j] = (size_t)(hg * 128 + bg * 8) * 10 + rem;
        const int u2 = rem * 2, b_loc = u2 / 20, u = u2 % 20;
        const int k = hg * 20 + u;
        S.aoffHi[j] = region + ((k >> 5) * 8 + ((k >> 3) & 3)) * 256
                    + b_loc * 16 + (k & 7) * 2;
        if (ok) S.pend0 |= 1u << j;
    }
}

__device__ __forceinline__ void stage_poll(const StageCtx& S,
                                           const unsigned* __restrict__ slice,
                                           unsigned char* Ap)
{
    const unsigned long long* s64 = (const unsigned long long*)slice;
    unsigned long long val[5];
    unsigned pend = S.pend0;
    while (__any(pend != 0)) {
        unsigned long long w[5];
#pragma unroll
        for (int j = 0; j < 5; ++j)
            if (pend & (1u << j))
                w[j] = __hip_atomic_load(s64 + S.src64[j], __ATOMIC_RELAXED,
                                         __HIP_MEMORY_SCOPE_AGENT);
#pragma unroll
        for (int j = 0; j < 5; ++j)
            if (pend & (1u << j)) {
                const unsigned long long x = w[j];
                if ((unsigned)x != SENTP && (unsigned)(x >> 32) != SENTP) {
                    val[j] = x; pend &= ~(1u << j);
                }
            }
    }
#pragma unroll
    for (int j = 0; j < 5; ++j)
        if (S.pend0 & (1u << j)) {
            const unsigned p0 = (unsigned)val[j], p1 = (unsigned)(val[j] >> 32);
            *(unsigned*)(Ap + S.aoffHi[j])        = (p0 & 0xFFFFu) | (p1 << 16);
            *(unsigned*)(Ap + S.aoffHi[j] + 1024) = (p0 >> 16) | (p1 & 0xFFFF0000u);
        }
}

struct ECtx { int b[3]; int koff[3]; int aoff[3]; bool ok[3]; };

__device__ __forceinline__ void estage_init(ECtx& E, int tid)
{
#pragma unroll
    for (int j = 0; j < 3; ++j) {
        const int es = tid + 512 * j;
        E.ok[j] = (es < 1216);   // 8 b x 152 k-pairs (incl. 2 zero-pad pairs)
        const int bb = E.ok[j] ? es / 152 : 0;
        const int kp = E.ok[j] ? es % 152 : 0;
        const int k  = kp * 2;
        E.b[j]    = bb;
        E.koff[j] = k;
        E.aoff[j] = EOFF + ((k >> 5) * 8 + ((k >> 3) & 3)) * 256
                  + bb * 16 + (k & 7) * 2;
    }
}

__device__ __forceinline__ void estage(const ECtx& E, const int* __restrict__ tokL,
                                       const unsigned* __restrict__ embcv, int it,
                                       unsigned char* Ap)
{
#pragma unroll
    for (int j = 0; j < 3; ++j)
        if (E.ok[j]) {
            const int tok = tokL[E.b[j] * 512 + it];
            const unsigned long long w = *(const unsigned long long*)
                (embcv + (size_t)tok * KP + E.koff[j]);
            const unsigned p0 = (unsigned)w, p1 = (unsigned)(w >> 32);
            *(unsigned*)(Ap + E.aoff[j])        = (p0 & 0xFFFFu) | (p1 << 16);
            *(unsigned*)(Ap + E.aoff[j] + 1024) = (p0 >> 16) | (p1 & 0xFFFF0000u);
        }
}

// ---- L0 wave: one n-tile (4 units); e@Wih0 (3-pass) + h1@Whh0 (2-pass) ----
__device__ void fused_L0(int lane, int nt, int hg, int bg,
                         const unsigned* __restrict__ embcv,
                         const float* __restrict__ Wih0,
                         const float* __restrict__ Whh0,
                         const float* __restrict__ bih0,
                         const float* __restrict__ bhh0,
                         unsigned* __restrict__ h1p,
                         const unsigned* __restrict__ ssrc, int sreg, int sbase,
                         int snch, int sdel,
                         const ECtx& E, const int* __restrict__ tokL,
                         unsigned char* __restrict__ Abuf, float (*gd)[8][16])
{
    const int kg = lane >> 4, mm = lane & 15;

    short8 bhh[10], bih[10], bil[10];
#pragma unroll
    for (int kt = 0; kt < 10; ++kt) {
        const int c = nt * 16 + mm;
        const int grow = (c & 3) * H + hg * 20 + (c >> 2);
        short8 h_, ih_, il_;
#pragma unroll
        for (int e = 0; e < 8; ++e) {
            const int k = kt * 32 + kg * 8 + e;
            const float vh = (k < H) ? Whh0[(size_t)grow * H + k] : 0.f;
            const float vi = (k < H) ? Wih0[(size_t)grow * H + k] : 0.f;
            h_[e] = (short)bf16_rn(vh);
            const unsigned short i16 = bf16_rn(vi);
            ih_[e] = (short)i16;
            il_[e] = (short)bf16_rn(vi - bf16_f(i16));
        }
        bhh[kt] = h_; bih[kt] = ih_; bil[kt] = il_;
    }

    StageCtx S; stage_init(S, lane, bg, sbase, snch, sreg);

    const bool upd = lane < 32;
    const int b_u = lane >> 2, u4 = lane & 3;
    const int u_loc = nt * 4 + u4;
    float bias[4];
#pragma unroll
    for (int g = 0; g < 4; ++g)
        bias[g] = bih0[g * H + hg * 20 + u_loc] + bhh0[g * H + hg * 20 + u_loc];
    float cst = 0.f;
    unsigned* hst = h1p + ((size_t)hg * 128 + bg * 8 + b_u) * 20 + u_loc;

    for (int it = 0; it <= T; ++it) {
        unsigned char* Ap = Abuf + (it & 1) * APARF;
        if (it < T) estage(E, tokL, embcv, it, Ap);
        if (it >= sdel) stage_poll(S, ssrc + (size_t)(it - sdel) * TSEG, Ap);
        __syncthreads();

        if (it < T) {
            f32x4 acc = (f32x4){0.f, 0.f, 0.f, 0.f};
#pragma unroll
            for (int kt = 0; kt < 10; ++kt) {
                const int boff = (kt * 8 + kg) * 256 + mm * 16;
                const short8 eh = *(const short8*)(Ap + EOFF + boff);
                const short8 el = *(const short8*)(Ap + EOFF + boff + 1024);
                const short8 hh = *(const short8*)(Ap + boff);
                const short8 hl = *(const short8*)(Ap + boff + 1024);
                acc = __builtin_amdgcn_mfma_f32_16x16x32_bf16(eh, bih[kt], acc, 0, 0, 0);
                acc = __builtin_amdgcn_mfma_f32_16x16x32_bf16(el, bih[kt], acc, 0, 0, 0);
                acc = __builtin_amdgcn_mfma_f32_16x16x32_bf16(eh, bil[kt], acc, 0, 0, 0);
                acc = __builtin_amdgcn_mfma_f32_16x16x32_bf16(hh, bhh[kt], acc, 0, 0, 0);
                acc = __builtin_amdgcn_mfma_f32_16x16x32_bf16(hl, bhh[kt], acc, 0, 0, 0);
            }
            if (lane < 32) {
                const int br = (lane >> 4) * 4;
#pragma unroll
                for (int r = 0; r < 4; ++r) gd[nt][br + r][mm] = acc[r];
            }
            if (upd) {
                const float* g4 = &gd[nt][b_u][u4 * 4];
                const float gi = bias[0] + g4[0], gf = bias[1] + g4[1];
                const float gz = bias[2] + g4[2], go = bias[3] + g4[3];
                const float iG = sigm(gi), fG = sigm(gf);
                const float zG = tanhfast(gz), oG = sigm(go);
                cst = fmaf(fG, cst, iG * zG);
                const float hv = oG * tanhfast(cst);
                __hip_atomic_store(hst + (size_t)it * TSEG, pack_hl(hv),
                                   __ATOMIC_RELAXED, __HIP_MEMORY_SCOPE_AGENT);
            }
        }
    }
}

// ---- L1 wave: NTL tiles; h1@Wih1 (2-pass) + h2@Whh1 (2-pass) per tile ------
template<int NTL>
__device__ void fused_L1(int lane, int t0, int hg, int bg,
                         const unsigned* __restrict__ embcv,
                         const float* __restrict__ Wih1,
                         const float* __restrict__ Whh1,
                         const float* __restrict__ bih1,
                         const float* __restrict__ bhh1,
                         unsigned* __restrict__ h2p,
                         const unsigned* __restrict__ ssrc, int sreg, int sbase,
                         int snch, int sdel,
                         const ECtx& E, const int* __restrict__ tokL,
                         unsigned char* __restrict__ Abuf, float (*gd)[8][16])
{
    const int kg = lane >> 4, mm = lane & 15;

    short8 bi[NTL][10], bh[NTL][10];
#pragma unroll
    for (int t = 0; t < NTL; ++t)
#pragma unroll
        for (int kt = 0; kt < 10; ++kt) {
            const int c = (t0 + t) * 16 + mm;
            const int grow = (c & 3) * H + hg * 20 + (c >> 2);
            short8 i_, h_;
#pragma unroll
            for (int e = 0; e < 8; ++e) {
                const int k = kt * 32 + kg * 8 + e;
                i_[e] = (short)bf16_rn((k < H) ? Wih1[(size_t)grow * H + k] : 0.f);
                h_[e] = (short)bf16_rn((k < H) ? Whh1[(size_t)grow * H + k] : 0.f);
            }
            bi[t][kt] = i_; bh[t][kt] = h_;
        }

    StageCtx S; stage_init(S, lane, bg, sbase, snch, sreg);

    const bool upd = lane < NTL * 32;
    const int tile = lane >> 5, lidx = lane & 31;
    const int b_u = lidx >> 2, u4 = lidx & 3;
    const int ntg = t0 + ((NTL > 1) ? tile : 0);
    const int u_loc = ntg * 4 + u4;
    float bias[4];
#pragma unroll
    for (int g = 0; g < 4; ++g)
        bias[g] = bih1[g * H + hg * 20 + u_loc] + bhh1[g * H + hg * 20 + u_loc];
    float cst = 0.f;
    unsigned* hst = h2p + ((size_t)hg * 128 + bg * 8 + b_u) * 20 + u_loc;

    for (int it = 0; it <= T; ++it) {
        unsigned char* Ap = Abuf + (it & 1) * APARF;
        if (it < T) estage(E, tokL, embcv, it, Ap);
        if (it >= sdel) stage_poll(S, ssrc + (size_t)(it - sdel) * TSEG, Ap);
        __syncthreads();

        if (it >= 1) {
            f32x4 acc[NTL];
#pragma unroll
            for (int t = 0; t < NTL; ++t) acc[t] = (f32x4){0.f, 0.f, 0.f, 0.f};
#pragma unroll
            for (int kt = 0; kt < 10; ++kt) {
                const int boff = (kt * 8 + kg) * 256 + mm * 16;
                const short8 x1h = *(const short8*)(Ap + boff);
                const short8 x1l = *(const short8*)(Ap + boff + 1024);
                const short8 x2h = *(const short8*)(Ap + A2OFF + boff);
                const short8 x2l = *(const short8*)(Ap + A2OFF + boff + 1024);
#pragma unroll
                for (int t = 0; t < NTL; ++t) {
                    acc[t] = __builtin_amdgcn_mfma_f32_16x16x32_bf16(x1h, bi[t][kt], acc[t], 0, 0, 0);
                    acc[t] = __builtin_amdgcn_mfma_f32_16x16x32_bf16(x1l, bi[t][kt], acc[t], 0, 0, 0);
                    acc[t] = __builtin_amdgcn_mfma_f32_16x16x32_bf16(x2h, bh[t][kt], acc[t], 0, 0, 0);
                    acc[t] = __builtin_amdgcn_mfma_f32_16x16x32_bf16(x2l, bh[t][kt], acc[t], 0, 0, 0);
                }
            }
            if (lane < 32) {
                const int br = (lane >> 4) * 4;
#pragma unroll
                for (int t = 0; t < NTL; ++t)
#pragma unroll
                    for (int r = 0; r < 4; ++r) gd[5 + t0 + t][br + r][mm] = acc[t][r];
            }
            if (upd) {
                const float* g4 = &gd[5 + ntg][b_u][u4 * 4];
                const float gi = bias[0] + g4[0], gf = bias[1] + g4[1];
                const float gz = bias[2] + g4[2], go = bias[3] + g4[3];
                const float iG = sigm(gi), fG = sigm(gf);
                const float zG = tanhfast(gz), oG = sigm(go);
                cst = fmaf(fG, cst, iG * zG);
                const float hv = oG * tanhfast(cst);
                __hip_atomic_store(hst + (size_t)(it - 1) * TSEG, pack_hl(hv),
                                   __ATOMIC_RELAXED, __HIP_MEMORY_SCOPE_AGENT);
            }
        }
    }
}

__global__ __launch_bounds__(512, 2)
void lstm_fused(const int* __restrict__ x,
                const unsigned* __restrict__ embcv,
                const float* __restrict__ Wih0, const float* __restrict__ Whh0,
                const float* __restrict__ bih0, const float* __restrict__ bhh0,
                const float* __restrict__ Wih1, const float* __restrict__ Whh1,
                const float* __restrict__ bih1, const float* __restrict__ bhh1,
                unsigned* __restrict__ h1p, unsigned* __restrict__ h2p)
{
    extern __shared__ unsigned char smem[];
    unsigned char* Abuf = smem;
    float (*gd)[8][16] = (float(*)[8][16])(smem + GDOFF);
    int* tokL = (int*)(smem + TOKOFF);

    const int tid = threadIdx.x, wv = tid >> 6, lane = tid & 63;
    const int hg = blockIdx.x % HGC, bg = blockIdx.x / HGC;

    for (int i = tid; i < FLDS / 16; i += 512)
        ((uint4*)smem)[i] = make_uint4(0, 0, 0, 0);
    __syncthreads();
    // preload tokens for this block's 8 batch rows: tokL[b][t]
    for (int idx = tid; idx < 8 * 512; idx += 512) {
        const int b = idx >> 9, tt = idx & 511;
        tokL[idx] = x[(size_t)(bg * 8 + b) * T + tt];
    }
    __syncthreads();

    ECtx E; estage_init(E, tid);

    // staging role (independent of compute role): wv0-3 -> h1 quarters (d=1),
    // wv4-7 -> h2 quarters (d=2)
    const int      sreg  = (wv < 4) ? 0 : A2OFF;
    const unsigned* ssrc = (wv < 4) ? h1p : h2p;
    const int      sbase = (wv & 3) * 4;
    const int      snch  = ((wv & 3) == 3) ? 3 : 4;
    const int      sdel  = (wv < 4) ? 1 : 2;

    if (wv < 5)
        fused_L0(lane, wv, hg, bg, embcv, Wih0, Whh0, bih0, bhh0, h1p,
                 ssrc, sreg, sbase, snch, sdel, E, tokL, Abuf, gd);
    else if (wv == 5)
        fused_L1<2>(lane, 0, hg, bg, embcv, Wih1, Whh1, bih1, bhh1, h2p,
                    ssrc, sreg, sbase, snch, sdel, E, tokL, Abuf, gd);
    else if (wv == 6)
        fused_L1<2>(lane, 2, hg, bg, embcv, Wih1, Whh1, bih1, bhh1, h2p,
                    ssrc, sreg, sbase, snch, sdel, E, tokL, Abuf, gd);
    else
        fused_L1<1>(lane, 4, hg, bg, embcv, Wih1, Whh1, bih1, bhh1, h2p,
                    ssrc, sreg, sbase, snch, sdel, E, tokL, Abuf, gd);
}

} // anonymous namespace

// ---------------------------------------------------------------------------
extern "C" void kernel_launch(void* const* d_in, const int* in_sizes, int n_in,
                              void* d_out, int out_size, void* d_ws, size_t ws_size,
                              hipStream_t stream)
{
    const int*   x    = (const int*)  d_in[0];
    const float* emb  = (const float*)d_in[1];
    const float* Wih0 = (const float*)d_in[2];
    const float* Whh0 = (const float*)d_in[3];
    const float* bih0 = (const float*)d_in[4];
    const float* bhh0 = (const float*)d_in[5];
    const float* Wih1 = (const float*)d_in[6];
    const float* Whh1 = (const float*)d_in[7];
    const float* bih1 = (const float*)d_in[8];
    const float* bhh1 = (const float*)d_in[9];
    const float* Wout = (const float*)d_in[10];
    const float* bout = (const float*)d_in[11];

    float* out = (float*)d_out;

    // d_ws layout: h1p, h2p (packed u32, 78.64 MB each), embcv, wcvo
    unsigned* h1p   = (unsigned*)d_ws;
    unsigned* h2p   = h1p + (size_t)T * TSEG;
    unsigned* embcv = h2p + (size_t)T * TSEG;
    unsigned* wcvo  = embcv + (size_t)NVOC * KP;

    // sentinel-fill both packed h buffers (data-as-flag protocol)
    const size_t nh4 = 2 * (size_t)T * TSEG / 4;
    sentinel_fill<<<dim3(2048), dim3(256), 0, stream>>>((uint4*)h1p, nh4);
    // preconvert emb and Wout to packed bf16 hi/lo planes (once per call)
    preconv<<<dim3(256), dim3(256), 0, stream>>>(emb,  embcv, NVOC);
    preconv<<<dim3(256), dim3(256), 0, stream>>>(Wout, wcvo,  NVOC);

    hipFuncSetAttribute(reinterpret_cast<const void*>(lstm_fused),
                        hipFuncAttributeMaxDynamicSharedMemorySize, FLDS);

    // fused two-layer recurrence with embedded xg0 (no standalone xg GEMM)
    lstm_fused<<<dim3(NWG), dim3(512), FLDS, stream>>>(
        x, embcv, Wih0, Whh0, bih0, bhh0, Wih1, Whh1, bih1, bhh1, h1p, h2p);

    // output projection from packed h2 and preconverted Wout
    gemm_pk<<<dim3(20, 512), dim3(256), 0, stream>>>(h2p, wcvo, bout, out, NVOC);
}